// Round 1
// baseline (432.292 us; speedup 1.0000x reference)
//
#include <hip/hip_runtime.h>
#include <hip/hip_bf16.h>

// Problem constants
#define BATCH 32
#define NSEQ  16384
#define DDIM  65
#define CHUNK 64
#define KQ    64
#define NBLK  256          // NSEQ / CHUNK
#define SCALE 0.12403473458920847f   // 65^-0.5
#define BSTRIDE 68         // blk row stride (elements), 136 B, 8B-aligned rows

typedef __bf16 bf16x8 __attribute__((ext_vector_type(8)));
typedef __bf16 bf16x4 __attribute__((ext_vector_type(4)));
typedef float  f32x4  __attribute__((ext_vector_type(4)));
#define MFMA16(a, b, c) __builtin_amdgcn_mfma_f32_16x16x32_bf16(a, b, c, 0, 0, 0)

__device__ __forceinline__ float gelu_exact(float v) {
    return 0.5f * v * (1.0f + erff(v * 0.7071067811865476f));
}

// tanh-approx GELU: |err| <= ~2e-4, far below bf16 rounding of keys/vals.
__device__ __forceinline__ float gelu_tanh(float x) {
    float x2 = x * x;
    float t  = 0.7978845608028654f * x * fmaf(0.044715f, x2, 1.0f);
    float e  = __expf(2.0f * t);
    float th = 1.0f - 2.0f * __builtin_amdgcn_rcpf(e + 1.0f);
    return 0.5f * x * (1.0f + th);
}

// direct global->LDS copy, 16 B per lane
__device__ __forceinline__ void load_lds16(const void* g, void* l) {
    __builtin_amdgcn_global_load_lds(
        (const __attribute__((address_space(1))) unsigned int*)g,
        (__attribute__((address_space(3))) unsigned int*)l, 16, 0, 0);
}

// ---------------------------------------------------------------------------
// Kernel 0: transpose+pad Wk,Wv to bf16 WT[80][64]: WT[d][e] = W[e][d], rows
// 65..79 zero.
// ---------------------------------------------------------------------------
__global__ __launch_bounds__(256) void k_prep(const float* __restrict__ Wk,
                                              const float* __restrict__ Wv,
                                              __bf16* __restrict__ WkT,
                                              __bf16* __restrict__ WvT) {
    int i = blockIdx.x * 256 + threadIdx.x;     // 0 .. 2*80*64-1
    if (i >= 2 * 80 * 64) return;
    int m = i / 5120;
    int j = i - m * 5120;
    int d = j >> 6, e = j & 63;
    const float* W = m ? Wv : Wk;
    __bf16* T = m ? WvT : WkT;
    T[(size_t)d * 64 + e] = (d < DDIM) ? (__bf16)W[e * DDIM + d] : (__bf16)0.0f;
}

// ---------------------------------------------------------------------------
// Kernel 1: per-slice partial sums over N (no atomics) + emit swizzled bf16
// copy of x (cols 0..63) and f32 column 64.  grid (64, 32).
// xbf[n][e] stores logical element (e ^ ((n&7)<<3)) -> 16B-block XOR swizzle
// so k_attn can global_load_lds linearly and ds_read conflict-free.
// ---------------------------------------------------------------------------
__global__ __launch_bounds__(256) void k_gavg(const float* __restrict__ x,
                                              float* __restrict__ partial,
                                              __bf16* __restrict__ xbf,
                                              float* __restrict__ x64g) {
    const int s = blockIdx.x;
    const int b = blockIdx.y;
    const int tid = threadIdx.x;
    const int w = tid >> 6, lane = tid & 63;
    const float* xb = x + (size_t)b * NSEQ * DDIM;
    const int n0 = s * 256;
    float acc = 0.f, acce = 0.f;
    #pragma unroll 4
    for (int i = 0; i < 64; ++i) {
        const int n = n0 + w + i * 4;
        const float* row = xb + (size_t)n * DDIM;
        const float v = row[lane];
        acc += v;
        xbf[((size_t)b * NSEQ + n) * 64 + (lane ^ ((n & 7) << 3))] = (__bf16)v;
        if (lane == 0) {
            const float ve = row[64];
            acce += ve;
            x64g[(size_t)b * NSEQ + n] = ve;
        }
    }
    __shared__ float part[4][DDIM];
    part[w][lane] = acc;
    if (lane == 0) part[w][64] = acce;
    __syncthreads();
    if (tid < DDIM) {
        partial[((size_t)b * 64 + s) * DDIM + tid] =
            part[0][tid] + part[1][tid] + part[2][tid] + part[3][tid];
    }
}

// ---------------------------------------------------------------------------
// Kernel 2a: reduce partials -> gavg; h = gelu(gavg@Wq1+bq1); r = gavg@Wr+br.
// grid 32.
// ---------------------------------------------------------------------------
__global__ __launch_bounds__(256) void k_qgen1(const float* __restrict__ partial,
    const float* __restrict__ Wq1, const float* __restrict__ bq1,
    const float* __restrict__ Wr,  const float* __restrict__ br,
    float* __restrict__ h_out, float* __restrict__ r_out) {
    const int b = blockIdx.x, tid = threadIdx.x;
    __shared__ float g[DDIM];
    if (tid < DDIM) {
        float a = 0.f;
        const float* p = partial + (size_t)b * 64 * DDIM + tid;
        #pragma unroll 8
        for (int s = 0; s < 64; ++s) a += p[s * DDIM];
        g[tid] = a * (1.0f / 16384.0f);
    }
    __syncthreads();
    if (tid < DDIM) {
        float a = bq1[tid];
        for (int e = 0; e < DDIM; ++e) a += g[e] * Wq1[e * DDIM + tid];
        h_out[b * DDIM + tid] = gelu_exact(a);
    } else if (tid >= 128 && tid < 128 + DDIM) {
        const int d = tid - 128;
        float a = br[d];
        for (int e = 0; e < DDIM; ++e) a += g[e] * Wr[e * DDIM + d];
        r_out[b * DDIM + d] = a;
    }
}

// ---------------------------------------------------------------------------
// Kernel 2b: q = (h@Wq2+bq2)*SCALE -> qbf [64][64] bf16 + q64 col.
// ---------------------------------------------------------------------------
__global__ __launch_bounds__(256) void k_qgen2(const float* __restrict__ h_in,
    const float* __restrict__ Wq2, const float* __restrict__ bq2,
    __bf16* __restrict__ qbf, float* __restrict__ q64) {
    const int b = blockIdx.y, tid = threadIdx.x;
    const int o = blockIdx.x * 256 + tid;
    __shared__ float h[DDIM];
    if (tid < DDIM) h[tid] = h_in[b * DDIM + tid];
    __syncthreads();
    if (o >= KQ * DDIM) return;
    float a = bq2[o];
    #pragma unroll 13
    for (int e = 0; e < DDIM; ++e) a += h[e] * Wq2[e * (KQ * DDIM) + o];
    a *= SCALE;
    const int k = o / DDIM, d = o - k * DDIM;
    if (d < 64) qbf[(size_t)b * 4096 + k * 64 + d] = (__bf16)a;
    else        q64[b * 64 + k] = a;
}

// ---------------------------------------------------------------------------
// Kernel 3 (MFMA): per (b, chunk).  All MFMA orientations chosen so outputs
// are lane-contiguous for their destination layout:
//   keys  = MFMA(WkT, x)  -> d-contiguous -> keys[c][d]  (b64 LDS writes)
//   vals  = MFMA(x, WvT)  -> c-contiguous -> valsT[d][c] (b64 LDS writes)
//   S^T   = MFMA(keys, q) -> lane-local softmax over c (2 shuffles)
//   blk^T = MFMA(valsT,P) -> d-contiguous -> blk[k][d]   (b64 global stores)
// LDS tiles are 128B-linear rows with XOR((row&7)<<4) swizzle: global_load_lds
// compatible + 2-way (free) bank conflicts.  24.5 KB LDS -> 6 blocks/CU.
// Only 2 barriers (P is written/read by the same wave's rows).
// ---------------------------------------------------------------------------
__global__ __launch_bounds__(256, 6) void k_attn(
    const __bf16* __restrict__ xbf, const float* __restrict__ x64g,
    const __bf16* __restrict__ qbf, const float* __restrict__ q64g,
    const __bf16* __restrict__ WkT, const __bf16* __restrict__ WvT,
    const float* __restrict__ Wk, const float* __restrict__ bkb,
    const float* __restrict__ Wv, const float* __restrict__ bvb,
    const float* __restrict__ pos, const float* __restrict__ cq,
    __bf16* __restrict__ blk_out, float* __restrict__ cs_out) {
    const int nb = blockIdx.x;
    const int b  = blockIdx.y;
    const int tid = threadIdx.x;
    const int lane = tid & 63, w = tid >> 6;
    const int l16 = lane & 15, quad = lane >> 4;

    __shared__ __align__(16) __bf16 xP[64 * 64];     // x chunk, then P (both swizzled)
    __shared__ __align__(16) __bf16 keysL[64 * 64];  // [c][d0..63] swizzled
    __shared__ __align__(16) __bf16 valsT[64 * 64];  // [d][c0..63] swizzled
    __shared__ __align__(16) __bf16 kcol64[64];      // keys[c][64]
    __shared__ __align__(16) __bf16 vcol64[64];      // vals[c][64]
    __shared__ float xs64[64];                       // x[c][64] fp32

    // hoisted q fragments (used in phase 3; loads overlap phase-1 wait)
    const int krow = w * 16 + l16;                   // this lane's k
    const __bf16* qr = qbf + (size_t)b * 4096 + krow * 64 + quad * 8;
    bf16x8 q0 = *(const bf16x8*)qr;
    bf16x8 q1 = *(const bf16x8*)(qr + 32);
    const float q64k = q64g[b * 64 + krow];

    // ---- phase 1: direct global->LDS of swizzled bf16 x chunk ----
    {
        const char* xg = (const char*)(xbf + ((size_t)b * NSEQ + (size_t)nb * CHUNK) * 64);
        char* lp = (char*)xP;
        #pragma unroll
        for (int j = 0; j < 2; ++j) {
            const int o = j * 4096 + w * 1024;
            load_lds16(xg + o + lane * 16, lp + o);
        }
        if (tid < 64) xs64[tid] = x64g[(size_t)b * NSEQ + (size_t)nb * CHUNK + tid];
    }
    __syncthreads();

    // ---- phase 2: keys/vals via MFMA + gelu, written pre-transposed ----
    {
        const int crow = w * 16 + l16;               // x-fragment row (c)
        const int sw_c = (crow & 7) << 4;
        const char* xrow = (const char*)xP + crow * 128;
        bf16x8 x0 = *(const bf16x8*)(xrow + ((quad * 16) ^ sw_c));
        bf16x8 x1 = *(const bf16x8*)(xrow + ((quad * 16 + 64) ^ sw_c));
        const float xe_c = xs64[crow];
        const f32x4 z = {0.f, 0.f, 0.f, 0.f};

        // keys: A=WkT (m=d), B=x (n=c) -> value r at d=16mt+4q+r, c=crow
        f32x4 kacc[5];
        #pragma unroll
        for (int mt = 0; mt < 5; ++mt) {
            const __bf16* wr = WkT + (mt * 16 + l16) * 64 + quad * 8;
            kacc[mt] = MFMA16(*(const bf16x8*)wr, x0, z);
            kacc[mt] = MFMA16(*(const bf16x8*)(wr + 32), x1, kacc[mt]);
        }
        #pragma unroll
        for (int mt = 0; mt < 4; ++mt) {
            const int d0 = mt * 16 + quad * 4;
            bf16x4 kv;
            #pragma unroll
            for (int r = 0; r < 4; ++r) {
                const int d = d0 + r;
                const float pre = kacc[mt][r] + xe_c * Wk[64 * DDIM + d] + bkb[d];
                kv[r] = (__bf16)(gelu_tanh(pre) + pos[crow * DDIM + d]);
            }
            *(bf16x4*)((char*)keysL + crow * 128 + ((d0 * 2) ^ sw_c)) = kv;
        }
        if (quad == 0) {  // d = 64 (mt=4, r=0)
            const float pre = kacc[4][0] + xe_c * Wk[64 * DDIM + 64] + bkb[64];
            kcol64[crow] = (__bf16)(gelu_tanh(pre) + pos[crow * DDIM + 64]);
        }

        // vals: A=x (m=c), B=WvT (n=d) -> value r at c=16w+4q+r, d=16nt+l16
        f32x4 vacc[5];
        #pragma unroll
        for (int nt = 0; nt < 5; ++nt) {
            const __bf16* wr = WvT + (nt * 16 + l16) * 64 + quad * 8;
            vacc[nt] = MFMA16(x0, *(const bf16x8*)wr, z);
            vacc[nt] = MFMA16(x1, *(const bf16x8*)(wr + 32), vacc[nt]);
        }
        const int cv0 = w * 16 + quad * 4;
        float xe4[4];
        #pragma unroll
        for (int r = 0; r < 4; ++r) xe4[r] = xs64[cv0 + r];
        #pragma unroll
        for (int nt = 0; nt < 4; ++nt) {
            const int d = nt * 16 + l16;
            const float wv64d = Wv[64 * DDIM + d], bvd = bvb[d];
            bf16x4 vv;
            #pragma unroll
            for (int r = 0; r < 4; ++r) {
                const float pre = vacc[nt][r] + xe4[r] * wv64d + bvd;
                vv[r] = (__bf16)(gelu_tanh(pre) + pos[(cv0 + r) * DDIM + d]);
            }
            *(bf16x4*)((char*)valsT + d * 128 + ((cv0 * 2) ^ ((d & 7) << 4))) = vv;
        }
        if (l16 == 0) {  // d = 64 (nt=4)
            const float wv64d = Wv[64 * DDIM + 64], bvd = bvb[64];
            bf16x4 vv;
            #pragma unroll
            for (int r = 0; r < 4; ++r) {
                const float pre = vacc[4][r] + xe4[r] * wv64d + bvd;
                vv[r] = (__bf16)(gelu_tanh(pre) + pos[(cv0 + r) * DDIM + 64]);
            }
            *(bf16x4*)((char*)vcol64 + cv0 * 2) = vv;
        }
    }
    __syncthreads();

    // ---- phase 3: S^T = keys@q^T (+d=64 fixup), lane-local softmax over c,
    //      P store (own rows), d=64 output column ----
    float inv_k, o64n;
    {
        const f32x4 z = {0.f, 0.f, 0.f, 0.f};
        float st[4][4];                  // value at c = 16mt+4q+r, k = krow
        #pragma unroll
        for (int mt = 0; mt < 4; ++mt) {
            const int cA = mt * 16 + l16;            // A-fragment row
            const char* kr = (const char*)keysL + cA * 128;
            const int swc = (cA & 7) << 4;
            f32x4 s = MFMA16(*(const bf16x8*)(kr + ((quad * 16) ^ swc)), q0, z);
            s = MFMA16(*(const bf16x8*)(kr + ((quad * 16 + 64) ^ swc)), q1, s);
            bf16x4 k4 = *(const bf16x4*)((const char*)kcol64 + (mt * 16 + quad * 4) * 2);
            #pragma unroll
            for (int r = 0; r < 4; ++r)
                st[mt][r] = fmaf(q64k, (float)k4[r], s[r]) * SCALE;
        }
        // softmax over c: 16 lane-local + cross-quad (xor16, xor32)
        float m = st[0][0];
        #pragma unroll
        for (int mt = 0; mt < 4; ++mt)
            #pragma unroll
            for (int r = 0; r < 4; ++r) m = fmaxf(m, st[mt][r]);
        m = fmaxf(m, __shfl_xor(m, 16));
        m = fmaxf(m, __shfl_xor(m, 32));
        float sum = 0.f;
        #pragma unroll
        for (int mt = 0; mt < 4; ++mt)
            #pragma unroll
            for (int r = 0; r < 4; ++r) {
                st[mt][r] = __expf(st[mt][r] - m);
                sum += st[mt][r];
            }
        sum += __shfl_xor(sum, 16);
        sum += __shfl_xor(sum, 32);
        inv_k = __builtin_amdgcn_rcpf(sum);

        // store unnormalized P (<=1) into own k-row of xP (swizzled)
        const int swk = (krow & 7) << 4;
        char* prow = (char*)xP + krow * 128;
        #pragma unroll
        for (int mt = 0; mt < 4; ++mt) {
            bf16x4 p4;
            #pragma unroll
            for (int r = 0; r < 4; ++r) p4[r] = (__bf16)st[mt][r];
            *(bf16x4*)(prow + (((mt * 16 + quad * 4) * 2) ^ swk)) = p4;
        }

        // d=64 output column from fp32 P
        float o = 0.f;
        #pragma unroll
        for (int mt = 0; mt < 4; ++mt) {
            bf16x4 v4 = *(const bf16x4*)((const char*)vcol64 + (mt * 16 + quad * 4) * 2);
            #pragma unroll
            for (int r = 0; r < 4; ++r) o = fmaf(st[mt][r], (float)v4[r], o);
        }
        o += __shfl_xor(o, 16);
        o += __shfl_xor(o, 32);
        o64n = o * inv_k;
        if (quad == 0)
            blk_out[(((size_t)b * NBLK + nb) * KQ + krow) * BSTRIDE + 64] = (__bf16)o64n;
    }
    // NO barrier: each wave reads back only the P rows it wrote.

    // ---- phase 4: blk^T = valsT@P -> d-contiguous b64 global stores + cs ----
    {
        const f32x4 z = {0.f, 0.f, 0.f, 0.f};
        const int swk = (krow & 7) << 4;
        const char* prow = (const char*)xP + krow * 128;
        bf16x8 p0 = *(const bf16x8*)(prow + ((quad * 16) ^ swk));
        bf16x8 p1 = *(const bf16x8*)(prow + ((quad * 16 + 64) ^ swk));
        const size_t obase = (((size_t)b * NBLK + nb) * KQ + krow) * BSTRIDE;
        float csp = 0.f;
        #pragma unroll
        for (int mt = 0; mt < 4; ++mt) {
            const int dA = mt * 16 + l16;            // A-fragment row (d)
            const char* vr = (const char*)valsT + dA * 128;
            const int swd = (dA & 7) << 4;
            f32x4 o = MFMA16(*(const bf16x8*)(vr + ((quad * 16) ^ swd)), p0, z);
            o = MFMA16(*(const bf16x8*)(vr + ((quad * 16 + 64) ^ swd)), p1, o);
            const int d0 = mt * 16 + quad * 4;       // output d base
            bf16x4 o4;
            #pragma unroll
            for (int r = 0; r < 4; ++r) {
                o4[r] = (__bf16)(o[r] * inv_k);
                csp = fmaf(o[r], cq[d0 + r], csp);
            }
            *(bf16x4*)((char*)blk_out + (obase + d0) * 2) = o4;
        }
        csp += __shfl_xor(csp, 16);
        csp += __shfl_xor(csp, 32);
        if (quad == 0) {
            const float cs = (csp * inv_k + cq[64] * o64n) * SCALE;
            cs_out[((size_t)b * KQ + krow) * NBLK + nb] = cs;
        }
    }
}

// ---------------------------------------------------------------------------
// Kernel 4: cross softmax over nb, weighted sum of blk, residual, LayerNorm.
// blk layout now [b][nb][k][BSTRIDE].
// ---------------------------------------------------------------------------
__global__ __launch_bounds__(256) void k_cross(
    const __bf16* __restrict__ blk, const float* __restrict__ cs,
    const float* __restrict__ r, const float* __restrict__ gamma,
    const float* __restrict__ beta, float* __restrict__ out) {
    const int bk_ = blockIdx.x;
    const int b = bk_ >> 6;
    const int k = bk_ & 63;
    const int tid = threadIdx.x;
    const int w = tid >> 6, lane = tid & 63;

    __shared__ float ew[NBLK];
    __shared__ float red[4][DDIM];
    __shared__ float vv[DDIM];
    __shared__ float wredA[4];
    __shared__ float stats[2];

    const float v = cs[(size_t)bk_ * NBLK + tid];
    float m = v;
    for (int off = 32; off; off >>= 1) m = fmaxf(m, __shfl_down(m, off));
    if (lane == 0) wredA[w] = m;
    __syncthreads();
    m = fmaxf(fmaxf(wredA[0], wredA[1]), fmaxf(wredA[2], wredA[3]));
    const float e = __expf(v - m);
    ew[tid] = e;
    float s = e;
    for (int off = 32; off; off >>= 1) s += __shfl_down(s, off);
    __syncthreads();
    if (lane == 0) wredA[w] = s;
    __syncthreads();
    const float inv = 1.0f / (wredA[0] + wredA[1] + wredA[2] + wredA[3]);

    const __bf16* base = blk + ((size_t)b * NBLK * KQ + k) * BSTRIDE;
    float acc = 0.f, acce = 0.f;
    #pragma unroll 4
    for (int i = 0; i < 64; ++i) {
        const int n = w + i * 4;
        const __bf16* row = base + (size_t)n * (KQ * BSTRIDE);
        const float wgt = ew[n];
        acc  += wgt * (float)row[lane];
        acce += wgt * (float)row[64];
    }
    red[w][lane] = acc;
    if (lane == 0) red[w][64] = acce;
    __syncthreads();
    if (tid < DDIM) {
        vv[tid] = (red[0][tid] + red[1][tid] + red[2][tid] + red[3][tid]) * inv
                  + r[b * DDIM + tid];
    }
    __syncthreads();
    if (tid < 64) {
        float a  = vv[tid] + (tid == 0 ? vv[64] : 0.f);
        float sq = vv[tid] * vv[tid] + (tid == 0 ? vv[64] * vv[64] : 0.f);
        for (int off = 32; off; off >>= 1) {
            a  += __shfl_down(a, off);
            sq += __shfl_down(sq, off);
        }
        if (tid == 0) {
            const float mu  = a * (1.0f / DDIM);
            const float var = sq * (1.0f / DDIM) - mu * mu;
            stats[0] = mu;
            stats[1] = rsqrtf(var + 1e-5f);
        }
    }
    __syncthreads();
    if (tid < DDIM) {
        out[(size_t)bk_ * DDIM + tid] =
            (vv[tid] - stats[0]) * stats[1] * gamma[tid] + beta[tid];
    }
}

// ---------------------------------------------------------------------------
extern "C" void kernel_launch(void* const* d_in, const int* in_sizes, int n_in,
                              void* d_out, int out_size, void* d_ws, size_t ws_size,
                              hipStream_t stream) {
    const float* x    = (const float*)d_in[0];
    const float* Wq1  = (const float*)d_in[1];
    const float* bq1  = (const float*)d_in[2];
    const float* Wq2  = (const float*)d_in[3];
    const float* bq2  = (const float*)d_in[4];
    const float* Wk   = (const float*)d_in[5];
    const float* bk   = (const float*)d_in[6];
    const float* Wv   = (const float*)d_in[7];
    const float* bv   = (const float*)d_in[8];
    const float* cq   = (const float*)d_in[9];
    const float* pos  = (const float*)d_in[10];
    const float* Wr   = (const float*)d_in[11];
    const float* br   = (const float*)d_in[12];
    const float* gamma= (const float*)d_in[13];
    const float* beta = (const float*)d_in[14];
    float* out = (float*)d_out;

    // workspace layout (byte offsets, all 16B-aligned)
    char* w8 = (char*)d_ws;
    float*  partial = (float*)w8;                    // 133120 f  @0
    float*  rres    = (float*)(w8 + 532480);         // 2080 f
    float*  q64     = (float*)(w8 + 540800);         // 2048 f
    float*  hbuf    = (float*)(w8 + 548992);         // 2080 f
    float*  cs      = (float*)(w8 + 557312);         // 524288 f
    __bf16* qbf     = (__bf16*)(w8 + 2654464);       // 131072 bf16
    __bf16* WkT     = (__bf16*)(w8 + 2916608);       // 5120 bf16
    __bf16* WvT     = (__bf16*)(w8 + 2926848);       // 5120 bf16
    float*  x64     = (float*)(w8 + 2937088);        // 524288 f
    __bf16* xbf     = (__bf16*)(w8 + 5034240);       // 33554432 bf16
    __bf16* blk     = (__bf16*)(w8 + 72143104);      // 35651584 bf16 ([b][nb][k][68])

    k_prep<<<40, 256, 0, stream>>>(Wk, Wv, WkT, WvT);
    k_gavg<<<dim3(64, BATCH), 256, 0, stream>>>(x, partial, xbf, x64);
    k_qgen1<<<BATCH, 256, 0, stream>>>(partial, Wq1, bq1, Wr, br, hbuf, rres);
    k_qgen2<<<dim3(17, BATCH), 256, 0, stream>>>(hbuf, Wq2, bq2, qbf, q64);
    k_attn<<<dim3(NBLK, BATCH), 256, 0, stream>>>(xbf, x64, qbf, q64, WkT, WvT,
                                                  Wk, bk, Wv, bv, pos, cq,
                                                  blk, cs);
    k_cross<<<BATCH * KQ, 256, 0, stream>>>(blk, cs, rres, gamma, beta, out);
}

// Round 2
// 387.441 us; speedup vs baseline: 1.1158x; 1.1158x over previous
//
#include <hip/hip_runtime.h>
#include <hip/hip_bf16.h>

// Problem constants
#define BATCH 32
#define NSEQ  16384
#define DDIM  65
#define CHUNK 64
#define KQ    64
#define NBLK  256          // NSEQ / CHUNK
#define SCALE 0.12403473458920847f   // 65^-0.5

typedef __bf16 bf16x8 __attribute__((ext_vector_type(8)));
typedef __bf16 bf16x4 __attribute__((ext_vector_type(4)));
typedef float  f32x4  __attribute__((ext_vector_type(4)));
#define MFMA16(a, b, c) __builtin_amdgcn_mfma_f32_16x16x32_bf16(a, b, c, 0, 0, 0)

__device__ __forceinline__ float gelu_exact(float v) {
    return 0.5f * v * (1.0f + erff(v * 0.7071067811865476f));
}

// tanh-approx GELU: |err| <= ~2e-4, far below bf16 rounding of keys/vals.
__device__ __forceinline__ float gelu_tanh(float x) {
    float x2 = x * x;
    float t  = 0.7978845608028654f * x * fmaf(0.044715f, x2, 1.0f);
    float e  = __expf(2.0f * t);
    float th = 1.0f - 2.0f * __builtin_amdgcn_rcpf(e + 1.0f);
    return 0.5f * x * (1.0f + th);
}

// ---------------------------------------------------------------------------
// Kernel 0: prep tables.
//  [0,10240)      WkT/WvT bf16 [80][64]: WT[d][e] = W[e][d], rows 65..79 = 0
//  [10240,14592)  posK f32 [64][68]: posK[c][d] = pos[c*65+d]   (d<65)
//  [14592,19012)  posV f32 [65][68]: posV[d][c] = pos[c*65+d]   (c<64)
//  [19012,19080)  wkc  f32 [68]: Wk[64*65+d]
//  [19080,19148)  wvc  f32 [68]: Wv[64*65+d]
// ---------------------------------------------------------------------------
__global__ __launch_bounds__(256) void k_prep(const float* __restrict__ Wk,
                                              const float* __restrict__ Wv,
                                              const float* __restrict__ pos,
                                              __bf16* __restrict__ WkT,
                                              __bf16* __restrict__ WvT,
                                              float* __restrict__ posK,
                                              float* __restrict__ posV,
                                              float* __restrict__ wkc,
                                              float* __restrict__ wvc) {
    int i = blockIdx.x * 256 + threadIdx.x;
    if (i < 10240) {
        int m = i / 5120;
        int j = i - m * 5120;
        int d = j >> 6, e = j & 63;
        const float* W = m ? Wv : Wk;
        __bf16* T = m ? WvT : WkT;
        T[(size_t)d * 64 + e] = (d < DDIM) ? (__bf16)W[e * DDIM + d] : (__bf16)0.0f;
    } else if (i < 14592) {
        int j = i - 10240;
        int c = j / 68, d = j - c * 68;
        posK[j] = (d < DDIM) ? pos[c * DDIM + d] : 0.f;
    } else if (i < 19012) {
        int j = i - 14592;
        int d = j / 68, c = j - d * 68;
        posV[j] = (d < DDIM && c < 64) ? pos[c * DDIM + d] : 0.f;
    } else if (i < 19080) {
        int d = i - 19012;
        wkc[d] = (d < DDIM) ? Wk[64 * DDIM + d] : 0.f;
    } else if (i < 19148) {
        int d = i - 19080;
        wvc[d] = (d < DDIM) ? Wv[64 * DDIM + d] : 0.f;
    }
}

// ---------------------------------------------------------------------------
// Kernel 1: per-slice partial sums over N (no atomics).  grid (64, 32).
// ---------------------------------------------------------------------------
__global__ __launch_bounds__(256) void k_gavg(const float* __restrict__ x,
                                              float* __restrict__ partial) {
    const int s = blockIdx.x;
    const int b = blockIdx.y;
    const int tid = threadIdx.x;
    const int w = tid >> 6, lane = tid & 63;
    const float* xb = x + (size_t)b * NSEQ * DDIM;
    const int n0 = s * 256;
    float acc = 0.f, acce = 0.f;
    #pragma unroll 4
    for (int i = 0; i < 64; ++i) {
        const float* row = xb + (size_t)(n0 + w + i * 4) * DDIM;
        acc  += row[lane];
        acce += row[64];
    }
    __shared__ float part[4][DDIM];
    part[w][lane] = acc;
    if (lane == 0) part[w][64] = acce;
    __syncthreads();
    if (tid < DDIM) {
        partial[((size_t)b * 64 + s) * DDIM + tid] =
            part[0][tid] + part[1][tid] + part[2][tid] + part[3][tid];
    }
}

// ---------------------------------------------------------------------------
// Kernel 2a: reduce partials -> gavg; h = gelu(gavg@Wq1+bq1); r = gavg@Wr+br.
// ---------------------------------------------------------------------------
__global__ __launch_bounds__(256) void k_qgen1(const float* __restrict__ partial,
    const float* __restrict__ Wq1, const float* __restrict__ bq1,
    const float* __restrict__ Wr,  const float* __restrict__ br,
    float* __restrict__ h_out, float* __restrict__ r_out) {
    const int b = blockIdx.x, tid = threadIdx.x;
    __shared__ float g[DDIM];
    if (tid < DDIM) {
        float a = 0.f;
        const float* p = partial + (size_t)b * 64 * DDIM + tid;
        #pragma unroll 8
        for (int s = 0; s < 64; ++s) a += p[s * DDIM];
        g[tid] = a * (1.0f / 16384.0f);
    }
    __syncthreads();
    if (tid < DDIM) {
        float a = bq1[tid];
        for (int e = 0; e < DDIM; ++e) a += g[e] * Wq1[e * DDIM + tid];
        h_out[b * DDIM + tid] = gelu_exact(a);
    } else if (tid >= 128 && tid < 128 + DDIM) {
        const int d = tid - 128;
        float a = br[d];
        for (int e = 0; e < DDIM; ++e) a += g[e] * Wr[e * DDIM + d];
        r_out[b * DDIM + d] = a;
    }
}

// ---------------------------------------------------------------------------
// Kernel 2b: q = (h@Wq2+bq2)*SCALE -> qbf [64][64] bf16 + q64 col.
// ---------------------------------------------------------------------------
__global__ __launch_bounds__(256) void k_qgen2(const float* __restrict__ h_in,
    const float* __restrict__ Wq2, const float* __restrict__ bq2,
    __bf16* __restrict__ qbf, float* __restrict__ q64) {
    const int b = blockIdx.y, tid = threadIdx.x;
    const int o = blockIdx.x * 256 + tid;
    __shared__ float h[DDIM];
    if (tid < DDIM) h[tid] = h_in[b * DDIM + tid];
    __syncthreads();
    if (o >= KQ * DDIM) return;
    float a = bq2[o];
    #pragma unroll 13
    for (int e = 0; e < DDIM; ++e) a += h[e] * Wq2[e * (KQ * DDIM) + o];
    a *= SCALE;
    const int k = o / DDIM, d = o - k * DDIM;
    if (d < 64) qbf[(size_t)b * 4096 + k * 64 + d] = (__bf16)a;
    else        q64[b * 64 + k] = a;
}

// ---------------------------------------------------------------------------
// Kernel 3 (MFMA): per (b, chunk).  MFMA orientations give lane-contiguous
// outputs; all ancillary data comes from aligned float4 table loads (posK,
// posV, wkc, wvc, bkb, bvb, cq) -- no scattered scalar dwords.
// LDS 25 KB; __launch_bounds__(256,5).  2 barriers.
// blk layout: [b][k][nb][64] (+ separate blk64 column array).
// ---------------------------------------------------------------------------
__global__ __launch_bounds__(256, 5) void k_attn(
    const float* __restrict__ x,
    const __bf16* __restrict__ qbf, const float* __restrict__ q64g,
    const __bf16* __restrict__ WkT, const __bf16* __restrict__ WvT,
    const float* __restrict__ posK, const float* __restrict__ posV,
    const float* __restrict__ wkc, const float* __restrict__ wvc,
    const float* __restrict__ bkb, const float* __restrict__ bvb,
    const float* __restrict__ cq,
    __bf16* __restrict__ blk_out, __bf16* __restrict__ blk64_out,
    float* __restrict__ cs_out) {
    const int nb = blockIdx.x;
    const int b  = blockIdx.y;
    const int tid = threadIdx.x;
    const int lane = tid & 63, w = tid >> 6;
    const int l16 = lane & 15, quad = lane >> 4;

    __shared__ __align__(16) __bf16 xP[64 * 64];     // x chunk, then P (swizzled)
    __shared__ __align__(16) __bf16 keysL[64 * 64];  // [c][d0..63] swizzled
    __shared__ __align__(16) __bf16 valsT[64 * 64];  // [d][c0..63] swizzled
    __shared__ __align__(16) __bf16 kcol64[64];      // keys[c][64]
    __shared__ __align__(16) __bf16 vcol64[64];      // vals[c][64]
    __shared__ float xs64[64];                       // x[c][64] fp32

    // hoisted q fragments (loads overlap phase 1)
    const int krow = w * 16 + l16;                   // this lane's k
    const __bf16* qr = qbf + (size_t)b * 4096 + krow * 64 + quad * 8;
    bf16x8 q0 = *(const bf16x8*)qr;
    bf16x8 q1 = *(const bf16x8*)(qr + 32);
    const float q64k = q64g[b * 64 + krow];

    // ---- phase 1: stage x chunk f32->bf16 into swizzled xP ----
    {
        const int c = tid >> 2, g = tid & 3;
        const float* xrow = x + ((size_t)b * NSEQ + (size_t)nb * CHUNK + c) * DDIM;
        const int sw = (c & 7) << 4;
        char* dst = (char*)xP + c * 128;
        #pragma unroll
        for (int j = 0; j < 16; ++j) {
            const int e = g + 4 * j;                 // coalesced: 4 consecutive per row
            const float v = xrow[e];
            *(__bf16*)(dst + ((((e >> 3) << 4) ^ sw) + (e & 7) * 2)) = (__bf16)v;
        }
        if (g == 0) xs64[c] = xrow[64];
    }
    __syncthreads();

    // ---- phase 2: keys/vals via MFMA + gelu, written pre-transposed ----
    {
        const int crow = w * 16 + l16;               // x-fragment row (c)
        const int sw_c = (crow & 7) << 4;
        const char* xrow = (const char*)xP + crow * 128;
        bf16x8 x0 = *(const bf16x8*)(xrow + ((quad * 16) ^ sw_c));
        bf16x8 x1 = *(const bf16x8*)(xrow + ((quad * 16 + 64) ^ sw_c));
        const float xe_c = xs64[crow];
        const f32x4 z = {0.f, 0.f, 0.f, 0.f};

        // keys: A=WkT (m=d), B=x (n=c) -> value r at d=16mt+4q+r, c=crow
        f32x4 kacc[5];
        #pragma unroll
        for (int mt = 0; mt < 5; ++mt) {
            const __bf16* wr = WkT + (mt * 16 + l16) * 64 + quad * 8;
            kacc[mt] = MFMA16(*(const bf16x8*)wr, x0, z);
            kacc[mt] = MFMA16(*(const bf16x8*)(wr + 32), x1, kacc[mt]);
        }
        #pragma unroll
        for (int mt = 0; mt < 4; ++mt) {
            const int d0 = mt * 16 + quad * 4;
            const f32x4 pk  = *(const f32x4*)(posK + crow * 68 + d0);
            const f32x4 wk4 = *(const f32x4*)(wkc + d0);
            const f32x4 bk4 = *(const f32x4*)(bkb + d0);
            bf16x4 kv;
            #pragma unroll
            for (int r = 0; r < 4; ++r) {
                const float pre = kacc[mt][r] + xe_c * wk4[r] + bk4[r];
                kv[r] = (__bf16)(gelu_tanh(pre) + pk[r]);
            }
            *(bf16x4*)((char*)keysL + crow * 128 + ((d0 * 2) ^ sw_c)) = kv;
        }
        if (quad == 0) {  // d = 64 (mt=4, r=0)
            const float pre = kacc[4][0] + xe_c * wkc[64] + bkb[64];
            kcol64[crow] = (__bf16)(gelu_tanh(pre) + posK[crow * 68 + 64]);
        }

        // vals: A=x (m=c), B=WvT (n=d) -> value r at c=16w+4q+r, d=16nt+l16
        f32x4 vacc[5];
        #pragma unroll
        for (int nt = 0; nt < 5; ++nt) {
            const __bf16* wr = WvT + (nt * 16 + l16) * 64 + quad * 8;
            vacc[nt] = MFMA16(x0, *(const bf16x8*)wr, z);
            vacc[nt] = MFMA16(x1, *(const bf16x8*)(wr + 32), vacc[nt]);
        }
        const int cv0 = w * 16 + quad * 4;
        float xe4[4];
        #pragma unroll
        for (int r = 0; r < 4; ++r) xe4[r] = xs64[cv0 + r];
        #pragma unroll
        for (int nt = 0; nt < 4; ++nt) {
            const int d = nt * 16 + l16;
            const float wvd = wvc[d], bvd = bvb[d];
            const f32x4 pv = *(const f32x4*)(posV + d * 68 + cv0);
            bf16x4 vv;
            #pragma unroll
            for (int r = 0; r < 4; ++r) {
                const float pre = vacc[nt][r] + xe4[r] * wvd + bvd;
                vv[r] = (__bf16)(gelu_tanh(pre) + pv[r]);
            }
            *(bf16x4*)((char*)valsT + d * 128 + ((cv0 * 2) ^ ((d & 7) << 4))) = vv;
        }
        if (l16 == 0) {  // d = 64 (nt=4)
            const float wvd = wvc[64], bvd = bvb[64];
            const f32x4 pv = *(const f32x4*)(posV + 64 * 68 + cv0);
            bf16x4 vv;
            #pragma unroll
            for (int r = 0; r < 4; ++r) {
                const float pre = vacc[4][r] + xe4[r] * wvd + bvd;
                vv[r] = (__bf16)(gelu_tanh(pre) + pv[r]);
            }
            *(bf16x4*)((char*)vcol64 + cv0 * 2) = vv;
        }
    }
    __syncthreads();

    // ---- phase 3: S^T = keys@q^T (+d=64 fixup), lane-local softmax over c,
    //      P store (own rows), d=64 output column ----
    float inv_k, o64n;
    {
        const f32x4 z = {0.f, 0.f, 0.f, 0.f};
        float st[4][4];                  // value at c = 16mt+4q+r, k = krow
        #pragma unroll
        for (int mt = 0; mt < 4; ++mt) {
            const int cA = mt * 16 + l16;            // A-fragment row
            const char* kr = (const char*)keysL + cA * 128;
            const int swc = (cA & 7) << 4;
            f32x4 s = MFMA16(*(const bf16x8*)(kr + ((quad * 16) ^ swc)), q0, z);
            s = MFMA16(*(const bf16x8*)(kr + ((quad * 16 + 64) ^ swc)), q1, s);
            bf16x4 k4 = *(const bf16x4*)((const char*)kcol64 + (mt * 16 + quad * 4) * 2);
            #pragma unroll
            for (int r = 0; r < 4; ++r)
                st[mt][r] = fmaf(q64k, (float)k4[r], s[r]) * SCALE;
        }
        // softmax over c: 16 lane-local + cross-quad (xor16, xor32)
        float m = st[0][0];
        #pragma unroll
        for (int mt = 0; mt < 4; ++mt)
            #pragma unroll
            for (int r = 0; r < 4; ++r) m = fmaxf(m, st[mt][r]);
        m = fmaxf(m, __shfl_xor(m, 16));
        m = fmaxf(m, __shfl_xor(m, 32));
        float sum = 0.f;
        #pragma unroll
        for (int mt = 0; mt < 4; ++mt)
            #pragma unroll
            for (int r = 0; r < 4; ++r) {
                st[mt][r] = __expf(st[mt][r] - m);
                sum += st[mt][r];
            }
        sum += __shfl_xor(sum, 16);
        sum += __shfl_xor(sum, 32);
        inv_k = __builtin_amdgcn_rcpf(sum);

        // store unnormalized P (<=1) into own k-row of xP (swizzled)
        const int swk = (krow & 7) << 4;
        char* prow = (char*)xP + krow * 128;
        #pragma unroll
        for (int mt = 0; mt < 4; ++mt) {
            bf16x4 p4;
            #pragma unroll
            for (int r = 0; r < 4; ++r) p4[r] = (__bf16)st[mt][r];
            *(bf16x4*)(prow + (((mt * 16 + quad * 4) * 2) ^ swk)) = p4;
        }

        // d=64 output column from fp32 P
        float o = 0.f;
        #pragma unroll
        for (int mt = 0; mt < 4; ++mt) {
            bf16x4 v4 = *(const bf16x4*)((const char*)vcol64 + (mt * 16 + quad * 4) * 2);
            #pragma unroll
            for (int r = 0; r < 4; ++r) o = fmaf(st[mt][r], (float)v4[r], o);
        }
        o += __shfl_xor(o, 16);
        o += __shfl_xor(o, 32);
        o64n = o * inv_k;
        if (quad == 0)
            blk64_out[((size_t)b * KQ + krow) * NBLK + nb] = (__bf16)o64n;
    }
    // NO barrier: each wave reads back only the P rows it wrote.

    // ---- phase 4: blk^T = valsT@P -> d-contiguous b64 global stores + cs ----
    {
        const f32x4 z = {0.f, 0.f, 0.f, 0.f};
        const int swk = (krow & 7) << 4;
        const char* prow = (const char*)xP + krow * 128;
        bf16x8 p0 = *(const bf16x8*)(prow + ((quad * 16) ^ swk));
        bf16x8 p1 = *(const bf16x8*)(prow + ((quad * 16 + 64) ^ swk));
        const size_t obase = (((size_t)b * KQ + krow) * NBLK + nb) * 64;
        const float cq64 = cq[64];
        float csp = 0.f;
        #pragma unroll
        for (int mt = 0; mt < 4; ++mt) {
            const int dA = mt * 16 + l16;            // A-fragment row (d)
            const char* vr = (const char*)valsT + dA * 128;
            const int swd = (dA & 7) << 4;
            f32x4 o = MFMA16(*(const bf16x8*)(vr + ((quad * 16) ^ swd)), p0, z);
            o = MFMA16(*(const bf16x8*)(vr + ((quad * 16 + 64) ^ swd)), p1, o);
            const int d0 = mt * 16 + quad * 4;       // output d base
            const f32x4 cq4 = *(const f32x4*)(cq + d0);
            bf16x4 o4;
            #pragma unroll
            for (int r = 0; r < 4; ++r) {
                o4[r] = (__bf16)(o[r] * inv_k);
                csp = fmaf(o[r], cq4[r], csp);
            }
            *(bf16x4*)((char*)blk_out + (obase + d0) * 2) = o4;
        }
        csp += __shfl_xor(csp, 16);
        csp += __shfl_xor(csp, 32);
        if (quad == 0) {
            const float cs = (csp * inv_k + cq64 * o64n) * SCALE;
            cs_out[((size_t)b * KQ + krow) * NBLK + nb] = cs;
        }
    }
}

// ---------------------------------------------------------------------------
// Kernel 4: cross softmax over nb, weighted sum of blk, residual, LayerNorm.
// blk layout [b][k][nb][64] + blk64 [b][k][nb]: fully streaming reads.
// ---------------------------------------------------------------------------
__global__ __launch_bounds__(256) void k_cross(
    const __bf16* __restrict__ blk, const __bf16* __restrict__ blk64,
    const float* __restrict__ cs,
    const float* __restrict__ r, const float* __restrict__ gamma,
    const float* __restrict__ beta, float* __restrict__ out) {
    const int bk_ = blockIdx.x;
    const int b = bk_ >> 6;
    const int tid = threadIdx.x;
    const int w = tid >> 6, lane = tid & 63;

    __shared__ float ew[NBLK];
    __shared__ float red[4][DDIM];
    __shared__ float vv[DDIM];
    __shared__ float wredA[4];
    __shared__ float stats[2];

    const float v = cs[(size_t)bk_ * NBLK + tid];
    float m = v;
    for (int off = 32; off; off >>= 1) m = fmaxf(m, __shfl_down(m, off));
    if (lane == 0) wredA[w] = m;
    __syncthreads();
    m = fmaxf(fmaxf(wredA[0], wredA[1]), fmaxf(wredA[2], wredA[3]));
    const float e = __expf(v - m);
    ew[tid] = e;
    float s = e;
    for (int off = 32; off; off >>= 1) s += __shfl_down(s, off);
    __syncthreads();
    if (lane == 0) wredA[w] = s;
    __syncthreads();
    const float inv = 1.0f / (wredA[0] + wredA[1] + wredA[2] + wredA[3]);

    const __bf16* base = blk + (size_t)bk_ * NBLK * 64;
    const __bf16* b64p = blk64 + (size_t)bk_ * NBLK;
    float acc = 0.f, acce = 0.f;
    #pragma unroll 4
    for (int i = 0; i < 64; ++i) {
        const int n = w + i * 4;
        const __bf16* row = base + n * 64;
        const float wgt = ew[n];
        acc  += wgt * (float)row[lane];
        acce += wgt * (float)b64p[n];
    }
    red[w][lane] = acc;
    if (lane == 0) red[w][64] = acce;
    __syncthreads();
    if (tid < DDIM) {
        vv[tid] = (red[0][tid] + red[1][tid] + red[2][tid] + red[3][tid]) * inv
                  + r[b * DDIM + tid];
    }
    __syncthreads();
    if (tid < 64) {
        float a  = vv[tid] + (tid == 0 ? vv[64] : 0.f);
        float sq = vv[tid] * vv[tid] + (tid == 0 ? vv[64] * vv[64] : 0.f);
        for (int off = 32; off; off >>= 1) {
            a  += __shfl_down(a, off);
            sq += __shfl_down(sq, off);
        }
        if (tid == 0) {
            const float mu  = a * (1.0f / DDIM);
            const float var = sq * (1.0f / DDIM) - mu * mu;
            stats[0] = mu;
            stats[1] = rsqrtf(var + 1e-5f);
        }
    }
    __syncthreads();
    if (tid < DDIM) {
        out[(size_t)bk_ * DDIM + tid] =
            (vv[tid] - stats[0]) * stats[1] * gamma[tid] + beta[tid];
    }
}

// ---------------------------------------------------------------------------
extern "C" void kernel_launch(void* const* d_in, const int* in_sizes, int n_in,
                              void* d_out, int out_size, void* d_ws, size_t ws_size,
                              hipStream_t stream) {
    const float* x    = (const float*)d_in[0];
    const float* Wq1  = (const float*)d_in[1];
    const float* bq1  = (const float*)d_in[2];
    const float* Wq2  = (const float*)d_in[3];
    const float* bq2  = (const float*)d_in[4];
    const float* Wk   = (const float*)d_in[5];
    const float* bk   = (const float*)d_in[6];
    const float* Wv   = (const float*)d_in[7];
    const float* bv   = (const float*)d_in[8];
    const float* cq   = (const float*)d_in[9];
    const float* pos  = (const float*)d_in[10];
    const float* Wr   = (const float*)d_in[11];
    const float* br   = (const float*)d_in[12];
    const float* gamma= (const float*)d_in[13];
    const float* beta = (const float*)d_in[14];
    float* out = (float*)d_out;

    // workspace layout (byte offsets, all 16B-aligned)
    char* w8 = (char*)d_ws;
    float*  partial = (float*)w8;                    // 532480 B @0
    float*  rres    = (float*)(w8 + 532480);         // 8320 B
    float*  q64     = (float*)(w8 + 540800);         // 8192 B
    float*  hbuf    = (float*)(w8 + 548992);         // 8320 B
    float*  cs      = (float*)(w8 + 557312);         // 2097152 B
    __bf16* qbf     = (__bf16*)(w8 + 2654464);       // 262144 B
    __bf16* WkT     = (__bf16*)(w8 + 2916608);       // 10240 B
    __bf16* WvT     = (__bf16*)(w8 + 2926848);       // 10240 B
    float*  posK    = (float*)(w8 + 2937088);        // 17408 B
    float*  posV    = (float*)(w8 + 2954496);        // 17680 B
    float*  wkc     = (float*)(w8 + 2972176);        // 272 B
    float*  wvc     = (float*)(w8 + 2972448);        // 272 B
    __bf16* blk     = (__bf16*)(w8 + 2972720);       // 67108864 B ([b][k][nb][64])
    __bf16* blk64   = (__bf16*)(w8 + 70081584);      // 1048576 B ([b][k][nb])

    k_prep<<<75, 256, 0, stream>>>(Wk, Wv, pos, WkT, WvT, posK, posV, wkc, wvc);
    k_gavg<<<dim3(64, BATCH), 256, 0, stream>>>(x, partial);
    k_qgen1<<<BATCH, 256, 0, stream>>>(partial, Wq1, bq1, Wr, br, hbuf, rres);
    k_qgen2<<<dim3(17, BATCH), 256, 0, stream>>>(hbuf, Wq2, bq2, qbf, q64);
    k_attn<<<dim3(NBLK, BATCH), 256, 0, stream>>>(x, qbf, q64, WkT, WvT,
                                                  posK, posV, wkc, wvc,
                                                  bk, bv, cq, blk, blk64, cs);
    k_cross<<<BATCH * KQ, 256, 0, stream>>>(blk, blk64, cs, rres, gamma, beta, out);
}